// Round 2
// baseline (5857.789 us; speedup 1.0000x reference)
//
#include <hip/hip_runtime.h>
#include <hip/hip_bf16.h>
#include <math.h>

#pragma clang fp contract(off)

namespace {

constexpr int kB     = 8192;
constexpr int kNV    = 256;
constexpr int kSteps = 32;

// ---- workspace layout (float slots) ----
constexpr size_t OFF_TEMPS = 0;        // 32 floats
constexpr size_t OFF_KEYS  = 64;       // 194 u32 stored here
constexpr size_t OFF_BSUM  = 512;      // 8192
constexpr size_t OFF_S0    = 8704;     // 8192
constexpr size_t OFF_WT    = 16896;    // 65536
constexpr size_t OFF_X1    = 82432;    // 8192*64 = 524288
constexpr size_t OFF_BMOD  = 606720;   // 2097152
constexpr size_t OFF_CMOD  = 2703872;  // 2097152
constexpr size_t OFF_V     = 4801024;  // 2097152
constexpr size_t OFF_H     = 6898176;  // 2097152
constexpr size_t WS_FLOATS = 8995328;  // ~36 MB

// ================= threefry2x32 (JAX semantics) =================
__device__ __forceinline__ unsigned rotl32(unsigned v, int n) {
  return (v << n) | (v >> (32 - n));
}

__device__ __forceinline__ void tf_block(unsigned k0, unsigned k1,
                                         unsigned c0, unsigned c1,
                                         unsigned* o0, unsigned* o1) {
  unsigned k2 = k0 ^ k1 ^ 0x1BD11BDAu;
  unsigned x0 = c0 + k0;
  unsigned x1 = c1 + k1;
  // group 1
  x0 += x1; x1 = rotl32(x1, 13); x1 ^= x0;
  x0 += x1; x1 = rotl32(x1, 15); x1 ^= x0;
  x0 += x1; x1 = rotl32(x1, 26); x1 ^= x0;
  x0 += x1; x1 = rotl32(x1, 6);  x1 ^= x0;
  x0 += k1; x1 += k2 + 1u;
  // group 2
  x0 += x1; x1 = rotl32(x1, 17); x1 ^= x0;
  x0 += x1; x1 = rotl32(x1, 29); x1 ^= x0;
  x0 += x1; x1 = rotl32(x1, 16); x1 ^= x0;
  x0 += x1; x1 = rotl32(x1, 24); x1 ^= x0;
  x0 += k2; x1 += k0 + 2u;
  // group 3
  x0 += x1; x1 = rotl32(x1, 13); x1 ^= x0;
  x0 += x1; x1 = rotl32(x1, 15); x1 ^= x0;
  x0 += x1; x1 = rotl32(x1, 26); x1 ^= x0;
  x0 += x1; x1 = rotl32(x1, 6);  x1 ^= x0;
  x0 += k0; x1 += k1 + 3u;
  // group 4
  x0 += x1; x1 = rotl32(x1, 17); x1 ^= x0;
  x0 += x1; x1 = rotl32(x1, 29); x1 ^= x0;
  x0 += x1; x1 = rotl32(x1, 16); x1 ^= x0;
  x0 += x1; x1 = rotl32(x1, 24); x1 ^= x0;
  x0 += k1; x1 += k2 + 4u;
  // group 5
  x0 += x1; x1 = rotl32(x1, 13); x1 ^= x0;
  x0 += x1; x1 = rotl32(x1, 15); x1 ^= x0;
  x0 += x1; x1 = rotl32(x1, 26); x1 ^= x0;
  x0 += x1; x1 = rotl32(x1, 6);  x1 ^= x0;
  x0 += k2; x1 += k0 + 5u;
  *o0 = x0; *o1 = x1;
}

// partitionable random_bits: counter=(0, idx), bits = o0 ^ o1
__device__ __forceinline__ float tf_uniform(unsigned k0, unsigned k1, unsigned idx) {
  unsigned o0, o1;
  tf_block(k0, k1, 0u, idx, &o0, &o1);
  unsigned bits = o0 ^ o1;
  float f = __uint_as_float((bits >> 9) | 0x3f800000u);
  return f - 1.0f;
}

// ================= XLA CPU math replicas =================
// XLA CPU vectorized expf (Cephes style), plain mul/add (no FMA).
// (kept for the exp-form-logistic fallback axis)
__device__ __forceinline__ float xla_expf(float x) {
  float cl = fminf(fmaxf(x, -88.3762626647949f), 88.3762626647950f);
  float fx = floorf(cl * 1.44269504088896341f + 0.5f);
  float tmp = 0.693359375f * fx;
  float z2 = -2.12194440e-4f * fx;
  float r = cl - tmp;
  r = r - z2;
  float zz = r * r;
  float y = 1.9875691500e-4f;
  y = y * r + 1.3981999507e-3f;
  y = y * r + 8.3334519073e-3f;
  y = y * r + 4.1665795894e-2f;
  y = y * r + 1.6666665459e-1f;
  y = y * r + 5.0000001201e-1f;
  y = y * zz + r;
  y = y + 1.0f;
  int n = (int)fx;
  float twon = __uint_as_float((unsigned)((n + 127) << 23));
  float res = y * twon;
  return fmaxf(res, x);
}

// XLA EmitFastTanh (f32), plain mul/add.
__device__ __forceinline__ float xla_tanhf(float x) {
  if (fabsf(x) < 0.0004f) return x;
  float xc = fminf(fmaxf(x, -9.0f), 9.0f);
  float x2 = xc * xc;
  float num = -2.76076847742355e-16f;
  num = num * x2 + 2.00018790482477e-13f;
  num = num * x2 + -8.60467152213735e-11f;
  num = num * x2 + 5.12229709037114e-08f;
  num = num * x2 + 1.48572235717979e-05f;
  num = num * x2 + 6.37261928875436e-04f;
  num = num * x2 + 4.89352455891786e-03f;
  num = xc * num;
  float den = 1.19825839466702e-06f;
  den = den * x2 + 1.18534705686654e-04f;
  den = den * x2 + 2.26843463243900e-03f;
  den = den * x2 + 4.89352518554385e-03f;
  return num / den;
}

// XLA elemental kLogistic: 0.5 + 0.5 * tanh(0.5 * x), tanh = EmitFastTanh.
__device__ __forceinline__ float xla_sigmoid(float x) {
  return 0.5f + 0.5f * xla_tanhf(0.5f * x);
}

// ================= kernels =================
// temps + key schedule. partitionable fold-like split: child i = block(key, 0, i)
__global__ __launch_bounds__(64) void kInitMeta(float* temps, unsigned* keys) {
  int t = threadIdx.x;
  if (t < 32) {
    // constant-folded by XLA with correctly-rounded host expf -> emulate via f64
    float tf = (float)t;
    float arg = 0.1f * (tf - 16.0f);
    float e = (float)exp((double)arg);
    float s = 1.0f / (1.0f + e);
    temps[t] = 1.0f + 4.0f * s;
  }
  if (t == 0) {
    unsigned cur0 = 0u, cur1 = 42u;  // jax.random.key(42) -> (hi, lo)
    unsigned a0, a1, b0, b1;
    tf_block(cur0, cur1, 0u, 0u, &a0, &a1);  // new key
    tf_block(cur0, cur1, 0u, 1u, &b0, &b1);  // k0 (init-v key)
    keys[0] = b0; keys[1] = b1;
    cur0 = a0; cur1 = a1;
    for (int st = 0; st < kSteps; ++st) {
      unsigned n0, n1, kh0, kh1, ks0a, ks0b, kv0, kv1;
      tf_block(cur0, cur1, 0u, 0u, &n0, &n1);
      tf_block(cur0, cur1, 0u, 1u, &kh0, &kh1);
      tf_block(cur0, cur1, 0u, 2u, &ks0a, &ks0b);
      tf_block(cur0, cur1, 0u, 3u, &kv0, &kv1);
      keys[2 + st * 6 + 0] = kh0;  keys[2 + st * 6 + 1] = kh1;
      keys[2 + st * 6 + 2] = ks0a; keys[2 + st * 6 + 3] = ks0b;
      keys[2 + st * 6 + 4] = kv0;  keys[2 + st * 6 + 5] = kv1;
      cur0 = n0; cur1 = n1;
    }
  }
}

__global__ __launch_bounds__(256) void kWt(const float* __restrict__ W, float* __restrict__ Wt) {
  int idx = blockIdx.x * 256 + threadIdx.x;  // 65536
  int r = idx / 256, c = idx % 256;
  Wt[r * 256 + c] = W[c * 256 + r];
}

__global__ __launch_bounds__(256) void kX1(const float* __restrict__ cond,
                                           const float* __restrict__ fc1w,
                                           const float* __restrict__ fc1b,
                                           float* __restrict__ x1) {
  int idx = blockIdx.x * 256 + threadIdx.x;  // 524288
  int b = idx / 64, hh = idx % 64;
  float acc = 0.0f;
  for (int k = 0; k < 16; ++k)
    acc = acc + cond[b * 16 + k] * fc1w[hh * 16 + k];
  acc = acc + fc1b[hh];
  x1[idx] = xla_tanhf(acc);
}

__global__ __launch_bounds__(256) void kMod(const float* __restrict__ x1,
                                            const float* __restrict__ fc2w,
                                            const float* __restrict__ fc2b,
                                            const float* __restrict__ bvec,
                                            const float* __restrict__ cvec,
                                            float* __restrict__ bmod,
                                            float* __restrict__ cmod) {
  int idx = blockIdx.x * 256 + threadIdx.x;  // 8192*512
  int b = idx / 512, t = idx % 512;
  int half = t / 256, ii = t % 256;
  int og = half * 512 + ii;   // gamma column
  int ob = og + 256;          // beta column
  float dg = 0.0f, db = 0.0f;
  for (int k = 0; k < 64; ++k) {
    float xv = x1[b * 64 + k];
    dg = dg + xv * fc2w[og * 64 + k];
    db = db + xv * fc2w[ob * 64 + k];
  }
  dg = dg + fc2b[og];
  db = db + fc2b[ob];
  float base = half ? cvec[ii] : bvec[ii];
  float outv = (1.0f + dg) * base + db;
  if (half) cmod[b * 256 + ii] = outv;
  else      bmod[b * 256 + ii] = outv;
}

__global__ __launch_bounds__(256) void kBsum(const float* __restrict__ bmod,
                                             float* __restrict__ bsum) {
  int b = blockIdx.x * 256 + threadIdx.x;
  if (b < kB) {
    float s = 0.0f;
    for (int i = 0; i < kNV; ++i) s = s + bmod[b * 256 + i];
    bsum[b] = s;
  }
}

__global__ __launch_bounds__(256) void kInitV(float* __restrict__ v,
                                              float* __restrict__ s0v,
                                              const unsigned* __restrict__ keys) {
  int idx = blockIdx.x * 256 + threadIdx.x;  // 2097152
  unsigned k00 = keys[0], k01 = keys[1];
  float u = tf_uniform(k00, k01, (unsigned)idx);
  v[idx] = (u < 0.5f) ? 1.0f : 0.0f;
  if (idx < kB) s0v[idx] = 1.0f;
}

// p_h = sigmoid((v_eff @ W + c_mod)/T); h = bern(kh)
__global__ __launch_bounds__(256) void kH(const float* __restrict__ W,
                                          const float* __restrict__ v,
                                          const float* __restrict__ s0v,
                                          const float* __restrict__ cmod,
                                          float* __restrict__ h,
                                          const unsigned* __restrict__ keys,
                                          const float* __restrict__ temps,
                                          int step) {
  constexpr int ROWS = 16;
  __shared__ float wlds[32][256];
  __shared__ float velds[ROWS][257];
  const int j = threadIdx.x;
  const int brow = blockIdx.x * ROWS;
  const float T = temps[step];
  const unsigned kh0 = keys[2 + step * 6 + 0];
  const unsigned kh1 = keys[2 + step * 6 + 1];

  for (int r = 0; r < ROWS; ++r) {
    int b = brow + r;
    float vv = v[b * 256 + j];
    float s = s0v[b];
    velds[r][j] = s * vv + (1.0f - s) * (1.0f - vv);
  }
  float acc[ROWS];
  for (int r = 0; r < ROWS; ++r) acc[r] = 0.0f;

  for (int kc = 0; kc < 256; kc += 32) {
    for (int kk = 0; kk < 32; ++kk)
      wlds[kk][j] = W[(kc + kk) * 256 + j];
    __syncthreads();
    for (int kk = 0; kk < 32; ++kk) {
      float wv = wlds[kk][j];
      for (int r = 0; r < ROWS; ++r)
        acc[r] = acc[r] + velds[r][kc + kk] * wv;  // ascending-k mul+add chain
    }
    __syncthreads();
  }
  for (int r = 0; r < ROWS; ++r) {
    int b = brow + r;
    float z = (acc[r] + cmod[b * 256 + j]) / T;
    float p = xla_sigmoid(z);
    float u = tf_uniform(kh0, kh1, (unsigned)(b * 256 + j));
    h[b * 256 + j] = (u < p) ? 1.0f : 0.0f;
  }
}

// a = h @ W^T ; row reduces ; s0 draw ; p_v ; v draw + symmetric flip
__global__ __launch_bounds__(256) void kAV(const float* __restrict__ Wt,
                                           const float* __restrict__ h,
                                           float* __restrict__ v,
                                           const float* __restrict__ bmod,
                                           const float* __restrict__ bsum,
                                           float* __restrict__ s0v,
                                           const unsigned* __restrict__ keys,
                                           const float* __restrict__ temps,
                                           int step) {
  constexpr int ROWS = 8;
  __shared__ float wtlds[16][256];
  __shared__ float hlds[ROWS][257];
  __shared__ float alds[ROWS][257];
  __shared__ float vlds[ROWS][257];
  __shared__ float bmlds[ROWS][257];
  __shared__ float s0lds[ROWS];
  const int i = threadIdx.x;
  const int brow = blockIdx.x * ROWS;
  const float T = temps[step];
  const unsigned ks0a = keys[2 + step * 6 + 2];
  const unsigned ks0b = keys[2 + step * 6 + 3];
  const unsigned kv0  = keys[2 + step * 6 + 4];
  const unsigned kv1  = keys[2 + step * 6 + 5];

  for (int r = 0; r < ROWS; ++r) {
    int b = brow + r;
    hlds[r][i]  = h[b * 256 + i];
    vlds[r][i]  = v[b * 256 + i];
    bmlds[r][i] = bmod[b * 256 + i];
  }
  float acc[ROWS];
  for (int r = 0; r < ROWS; ++r) acc[r] = 0.0f;

  for (int jc = 0; jc < 256; jc += 16) {
    for (int kk = 0; kk < 16; ++kk)
      wtlds[kk][i] = Wt[(jc + kk) * 256 + i];
    __syncthreads();
    for (int kk = 0; kk < 16; ++kk) {
      float wv = wtlds[kk][i];
      for (int r = 0; r < ROWS; ++r)
        acc[r] = acc[r] + hlds[r][jc + kk] * wv;  // ascending-j mul+add chain
    }
    __syncthreads();
  }
  for (int r = 0; r < ROWS; ++r) alds[r][i] = acc[r];
  __syncthreads();

  if (i < ROWS) {
    int b = brow + i;
    float vb = 0.0f, va = 0.0f, as = 0.0f;
    for (int k = 0; k < 256; ++k) {   // three independent sequential chains
      float av = alds[i][k];
      float vv = vlds[i][k];
      vb = vb + vv * bmlds[i][k];
      va = va + vv * av;
      as = as + av;
    }
    float dE = ((-bsum[b] - as) + 2.0f * vb) + 2.0f * va;
    float z = dE / T;
    float p = xla_sigmoid(z);
    float u = tf_uniform(ks0a, ks0b, (unsigned)b);
    float s0n = (u < p) ? 1.0f : 0.0f;
    s0lds[i] = s0n;
    s0v[b] = s0n;
  }
  __syncthreads();

  for (int r = 0; r < ROWS; ++r) {
    int b = brow + r;
    float z = (alds[r][i] + bmlds[r][i]) / T;
    float p = xla_sigmoid(z);
    float u = tf_uniform(kv0, kv1, (unsigned)(b * 256 + i));
    float ve2 = (u < p) ? 1.0f : 0.0f;
    float s0n = s0lds[r];
    v[b * 256 + i] = s0n * ve2 + (1.0f - s0n) * (1.0f - ve2);
  }
}

__global__ __launch_bounds__(256) void kOut(const float* __restrict__ v,
                                            const float* __restrict__ temps,
                                            float* __restrict__ out) {
  int bidx = blockIdx.x;
  int tid = threadIdx.x;
  if (bidx < 8192) {
    int idx = bidx * 256 + tid;
    out[idx] = v[idx];
  } else if (tid < 32) {
    out[2097152 + tid] = temps[tid];
  }
}

}  // namespace

extern "C" void kernel_launch(void* const* d_in, const int* in_sizes, int n_in,
                              void* d_out, int out_size, void* d_ws, size_t ws_size,
                              hipStream_t stream) {
  (void)in_sizes; (void)n_in; (void)out_size;
  const float* cond = (const float*)d_in[0];
  const float* W    = (const float*)d_in[1];
  const float* bvec = (const float*)d_in[2];
  const float* cvec = (const float*)d_in[3];
  const float* fc1w = (const float*)d_in[4];
  const float* fc1b = (const float*)d_in[5];
  const float* fc2w = (const float*)d_in[6];
  const float* fc2b = (const float*)d_in[7];

  if (ws_size < WS_FLOATS * sizeof(float)) return;  // fail visibly if ws too small

  float* ws    = (float*)d_ws;
  float* temps = ws + OFF_TEMPS;
  unsigned* keys = (unsigned*)(ws + OFF_KEYS);
  float* bsum  = ws + OFF_BSUM;
  float* s0v   = ws + OFF_S0;
  float* Wt    = ws + OFF_WT;
  float* x1    = ws + OFF_X1;
  float* bmod  = ws + OFF_BMOD;
  float* cmod  = ws + OFF_CMOD;
  float* v     = ws + OFF_V;
  float* h     = ws + OFF_H;
  float* out   = (float*)d_out;

  hipLaunchKernelGGL(kInitMeta, dim3(1), dim3(64), 0, stream, temps, keys);
  hipLaunchKernelGGL(kWt, dim3(256), dim3(256), 0, stream, W, Wt);
  hipLaunchKernelGGL(kX1, dim3(2048), dim3(256), 0, stream, cond, fc1w, fc1b, x1);
  hipLaunchKernelGGL(kMod, dim3(16384), dim3(256), 0, stream, x1, fc2w, fc2b, bvec, cvec, bmod, cmod);
  hipLaunchKernelGGL(kBsum, dim3(32), dim3(256), 0, stream, bmod, bsum);
  hipLaunchKernelGGL(kInitV, dim3(8192), dim3(256), 0, stream, v, s0v, keys);
  for (int t = 0; t < kSteps; ++t) {
    hipLaunchKernelGGL(kH, dim3(512), dim3(256), 0, stream, W, v, s0v, cmod, h, keys, temps, t);
    hipLaunchKernelGGL(kAV, dim3(1024), dim3(256), 0, stream, Wt, h, v, bmod, bsum, s0v, keys, temps, t);
  }
  hipLaunchKernelGGL(kOut, dim3(8193), dim3(256), 0, stream, v, temps, out);
}

// Round 3
// 2474.301 us; speedup vs baseline: 2.3675x; 2.3675x over previous
//
#include <hip/hip_runtime.h>
#include <math.h>

#pragma clang fp contract(off)

namespace {

constexpr int kSteps = 32;

// ---- workspace layout (float slots) ----
constexpr size_t OFF_TEMPS = 0;        // 32 floats
constexpr size_t OFF_KEYS  = 64;       // 194 u32
constexpr size_t OFF_WT    = 512;      // 65536
constexpr size_t OFF_F2T   = 66048;    // 65536
constexpr size_t OFF_X1    = 131584;   // 524288
constexpr size_t OFF_BMOD  = 655872;   // 2097152
constexpr size_t OFF_CMOD  = 2753024;  // 2097152
constexpr size_t WS_FLOATS = 4850176;  // ~19.4 MB

// ================= threefry2x32 (JAX semantics) =================
__device__ __forceinline__ unsigned rotl32(unsigned v, int n) {
  return (v << n) | (v >> (32 - n));
}

__device__ __forceinline__ void tf_block(unsigned k0, unsigned k1,
                                         unsigned c0, unsigned c1,
                                         unsigned* o0, unsigned* o1) {
  unsigned k2 = k0 ^ k1 ^ 0x1BD11BDAu;
  unsigned x0 = c0 + k0;
  unsigned x1 = c1 + k1;
  x0 += x1; x1 = rotl32(x1, 13); x1 ^= x0;
  x0 += x1; x1 = rotl32(x1, 15); x1 ^= x0;
  x0 += x1; x1 = rotl32(x1, 26); x1 ^= x0;
  x0 += x1; x1 = rotl32(x1, 6);  x1 ^= x0;
  x0 += k1; x1 += k2 + 1u;
  x0 += x1; x1 = rotl32(x1, 17); x1 ^= x0;
  x0 += x1; x1 = rotl32(x1, 29); x1 ^= x0;
  x0 += x1; x1 = rotl32(x1, 16); x1 ^= x0;
  x0 += x1; x1 = rotl32(x1, 24); x1 ^= x0;
  x0 += k2; x1 += k0 + 2u;
  x0 += x1; x1 = rotl32(x1, 13); x1 ^= x0;
  x0 += x1; x1 = rotl32(x1, 15); x1 ^= x0;
  x0 += x1; x1 = rotl32(x1, 26); x1 ^= x0;
  x0 += x1; x1 = rotl32(x1, 6);  x1 ^= x0;
  x0 += k0; x1 += k1 + 3u;
  x0 += x1; x1 = rotl32(x1, 17); x1 ^= x0;
  x0 += x1; x1 = rotl32(x1, 29); x1 ^= x0;
  x0 += x1; x1 = rotl32(x1, 16); x1 ^= x0;
  x0 += x1; x1 = rotl32(x1, 24); x1 ^= x0;
  x0 += k1; x1 += k2 + 4u;
  x0 += x1; x1 = rotl32(x1, 13); x1 ^= x0;
  x0 += x1; x1 = rotl32(x1, 15); x1 ^= x0;
  x0 += x1; x1 = rotl32(x1, 26); x1 ^= x0;
  x0 += x1; x1 = rotl32(x1, 6);  x1 ^= x0;
  x0 += k2; x1 += k0 + 5u;
  *o0 = x0; *o1 = x1;
}

__device__ __forceinline__ float tf_uniform(unsigned k0, unsigned k1, unsigned idx) {
  unsigned o0, o1;
  tf_block(k0, k1, 0u, idx, &o0, &o1);
  unsigned bits = o0 ^ o1;
  float f = __uint_as_float((bits >> 9) | 0x3f800000u);
  return f - 1.0f;
}

// XLA EmitFastTanh (f32), plain mul/add.
__device__ __forceinline__ float xla_tanhf(float x) {
  if (fabsf(x) < 0.0004f) return x;
  float xc = fminf(fmaxf(x, -9.0f), 9.0f);
  float x2 = xc * xc;
  float num = -2.76076847742355e-16f;
  num = num * x2 + 2.00018790482477e-13f;
  num = num * x2 + -8.60467152213735e-11f;
  num = num * x2 + 5.12229709037114e-08f;
  num = num * x2 + 1.48572235717979e-05f;
  num = num * x2 + 6.37261928875436e-04f;
  num = num * x2 + 4.89352455891786e-03f;
  num = xc * num;
  float den = 1.19825839466702e-06f;
  den = den * x2 + 1.18534705686654e-04f;
  den = den * x2 + 2.26843463243900e-03f;
  den = den * x2 + 4.89352518554385e-03f;
  return num / den;
}

// XLA elemental kLogistic: 0.5 + 0.5 * tanh(0.5 * x)
__device__ __forceinline__ float xla_sigmoid(float x) {
  return 0.5f + 0.5f * xla_tanhf(0.5f * x);
}

// ================= setup kernels =================
__global__ __launch_bounds__(64) void kInitMeta(float* temps, unsigned* keys) {
  int t = threadIdx.x;
  if (t < 32) {
    float tf = (float)t;
    float arg = 0.1f * (tf - 16.0f);
    float e = (float)exp((double)arg);  // constant-folded by XLA w/ host expf
    float s = 1.0f / (1.0f + e);
    temps[t] = 1.0f + 4.0f * s;
  }
  if (t == 0) {
    unsigned cur0 = 0u, cur1 = 42u;  // jax.random.key(42)
    unsigned a0, a1, b0, b1;
    tf_block(cur0, cur1, 0u, 0u, &a0, &a1);  // carried key
    tf_block(cur0, cur1, 0u, 1u, &b0, &b1);  // init-v key
    keys[0] = b0; keys[1] = b1;
    cur0 = a0; cur1 = a1;
    for (int st = 0; st < kSteps; ++st) {
      unsigned n0, n1, kh0, kh1, ks0a, ks0b, kv0, kv1;
      tf_block(cur0, cur1, 0u, 0u, &n0, &n1);
      tf_block(cur0, cur1, 0u, 1u, &kh0, &kh1);
      tf_block(cur0, cur1, 0u, 2u, &ks0a, &ks0b);
      tf_block(cur0, cur1, 0u, 3u, &kv0, &kv1);
      keys[2 + st * 6 + 0] = kh0;  keys[2 + st * 6 + 1] = kh1;
      keys[2 + st * 6 + 2] = ks0a; keys[2 + st * 6 + 3] = ks0b;
      keys[2 + st * 6 + 4] = kv0;  keys[2 + st * 6 + 5] = kv1;
      cur0 = n0; cur1 = n1;
    }
  }
}

__global__ __launch_bounds__(256) void kWt(const float* __restrict__ W, float* __restrict__ Wt) {
  int idx = blockIdx.x * 256 + threadIdx.x;  // 65536
  int r = idx >> 8, c = idx & 255;
  Wt[r * 256 + c] = W[c * 256 + r];
}

__global__ __launch_bounds__(256) void kTf2(const float* __restrict__ fc2w, float* __restrict__ fc2wT) {
  int idx = blockIdx.x * 256 + threadIdx.x;  // 65536
  int k = idx >> 10, o = idx & 1023;
  fc2wT[idx] = fc2w[o * 64 + k];             // fc2wT[k][o]
}

__global__ __launch_bounds__(256) void kX1(const float* __restrict__ cond,
                                           const float* __restrict__ fc1w,
                                           const float* __restrict__ fc1b,
                                           float* __restrict__ x1) {
  int idx = blockIdx.x * 256 + threadIdx.x;  // 524288
  int b = idx >> 6, hh = idx & 63;
  float acc = 0.0f;
  for (int k = 0; k < 16; ++k)
    acc = acc + cond[b * 16 + k] * fc1w[hh * 16 + k];
  acc = acc + fc1b[hh];
  x1[idx] = xla_tanhf(acc);
}

// coalesced via fc2wT; same (b,t) mapping and op order as the passing kMod
__global__ __launch_bounds__(256) void kMod2(const float* __restrict__ x1,
                                             const float* __restrict__ fc2wT,
                                             const float* __restrict__ fc2b,
                                             const float* __restrict__ bvec,
                                             const float* __restrict__ cvec,
                                             float* __restrict__ bmod,
                                             float* __restrict__ cmod) {
  const int bid = blockIdx.x;        // 16384
  const int b = bid >> 1;
  const int half = bid & 1;
  const int ii = threadIdx.x;
  const int og = half * 512 + ii;
  const int ob = og + 256;
  float dg = 0.0f, db = 0.0f;
  for (int k = 0; k < 64; ++k) {
    float xv = x1[b * 64 + k];
    dg = dg + xv * fc2wT[k * 1024 + og];
    db = db + xv * fc2wT[k * 1024 + ob];
  }
  dg = dg + fc2b[og];
  db = db + fc2b[ob];
  float base = half ? cvec[ii] : bvec[ii];
  float outv = (1.0f + dg) * base + db;
  if (half) cmod[b * 256 + ii] = outv;
  else      bmod[b * 256 + ii] = outv;
}

// ================= fused 32-step Gibbs kernel =================
// Block owns 8 batch rows for the whole chain. LDS ~33 KB -> 4 blocks/CU,
// grid 1024 all-resident. X buffer aliases veff -> h -> a per step.
__global__ __launch_bounds__(256, 4) void kGibbs(
    const float* __restrict__ W, const float* __restrict__ Wt,
    const float* __restrict__ bmod, const float* __restrict__ cmod,
    const unsigned* __restrict__ keys, const float* __restrict__ temps,
    float* __restrict__ out) {
  __shared__ float4 X4[8][65];       // row stride 260 floats, 16B-aligned
  __shared__ float  vlds[8][257];
  __shared__ float  bmlds[8][257];
  __shared__ float  cmlds[8][257];
  __shared__ float  chainres[8][3];
  __shared__ float  bsum_s[8];
  __shared__ int    s0i[8];

  float* Xf = reinterpret_cast<float*>(X4);

  const int j = threadIdx.x;
  const int brow = blockIdx.x * 8;

#pragma unroll
  for (int r = 0; r < 8; ++r) {
    bmlds[r][j] = bmod[(brow + r) * 256 + j];
    cmlds[r][j] = cmod[(brow + r) * 256 + j];
  }
  if (j < 8) s0i[j] = 1;
  {
    const unsigned k00 = keys[0], k01 = keys[1];
#pragma unroll
    for (int r = 0; r < 8; ++r) {
      float u = tf_uniform(k00, k01, (unsigned)((brow + r) * 256 + j));
      vlds[r][j] = (u < 0.5f) ? 1.0f : 0.0f;
    }
  }
  __syncthreads();
  if (j < 8) {  // bsum per row, sequential ascending (visible by step-0 bar6)
    float s = 0.0f;
    for (int k = 0; k < 256; ++k) s = s + bmlds[j][k];
    bsum_s[j] = s;
  }

  for (int t = 0; t < kSteps; ++t) {
    const float T = temps[t];
    const unsigned kh0 = keys[2 + t * 6 + 0], kh1 = keys[2 + t * 6 + 1];
    const unsigned ksa = keys[2 + t * 6 + 2], ksb = keys[2 + t * 6 + 3];
    const unsigned kv0 = keys[2 + t * 6 + 4], kv1 = keys[2 + t * 6 + 5];

    // (1) v_eff -> X   (s0 in {0,1}: select == s0*v+(1-s0)*(1-v) bit-exact)
#pragma unroll
    for (int r = 0; r < 8; ++r) {
      float vv = vlds[r][j];
      Xf[r * 260 + j] = s0i[r] ? vv : 1.0f - vv;
    }
    __syncthreads();  // bar1

    // (2) H MAC: acc[r] = sum_k veff[r][k]*W[k][j], ascending k, mul+add
    float acc[8];
#pragma unroll
    for (int r = 0; r < 8; ++r) acc[r] = 0.0f;
    {
      const float* wp = W + j;
      for (int kb = 0; kb < 64; ++kb) {
        const float* wq = wp + (kb << 10);
        float w0 = wq[0];
        float w1 = wq[256];
        float w2 = wq[512];
        float w3 = wq[768];
#pragma unroll
        for (int r = 0; r < 8; ++r) {
          float4 v4 = X4[r][kb];
          acc[r] = acc[r] + v4.x * w0;
          acc[r] = acc[r] + v4.y * w1;
          acc[r] = acc[r] + v4.z * w2;
          acc[r] = acc[r] + v4.w * w3;
        }
      }
    }

    // h draw (needs only acc+cmod; compute before the barrier for overlap)
    float hv[8];
#pragma unroll
    for (int r = 0; r < 8; ++r) {
      float z = (acc[r] + cmlds[r][j]) / T;
      float p = xla_sigmoid(z);
      float u = tf_uniform(kh0, kh1, (unsigned)((brow + r) * 256 + j));
      hv[r] = (u < p) ? 1.0f : 0.0f;
    }
    __syncthreads();  // bar2: all H-MAC reads of X complete
#pragma unroll
    for (int r = 0; r < 8; ++r) Xf[r * 260 + j] = hv[r];
    __syncthreads();  // bar3: h visible

    // (4) AV MAC: acc[r] = sum_jj h[r][jj]*W[i=j][jj], ascending jj
#pragma unroll
    for (int r = 0; r < 8; ++r) acc[r] = 0.0f;
    {
      const float* wp = Wt + j;
      for (int kb = 0; kb < 64; ++kb) {
        const float* wq = wp + (kb << 10);
        float w0 = wq[0];
        float w1 = wq[256];
        float w2 = wq[512];
        float w3 = wq[768];
#pragma unroll
        for (int r = 0; r < 8; ++r) {
          float4 v4 = X4[r][kb];
          acc[r] = acc[r] + v4.x * w0;
          acc[r] = acc[r] + v4.y * w1;
          acc[r] = acc[r] + v4.z * w2;
          acc[r] = acc[r] + v4.w * w3;
        }
      }
    }

    // v candidate draws (independent of s0) — off the critical path
    float ve2[8];
#pragma unroll
    for (int r = 0; r < 8; ++r) {
      float z = (acc[r] + bmlds[r][j]) / T;
      float p = xla_sigmoid(z);
      float u = tf_uniform(kv0, kv1, (unsigned)((brow + r) * 256 + j));
      ve2[r] = (u < p) ? 1.0f : 0.0f;
    }

    __syncthreads();  // bar4: AV reads of X complete
#pragma unroll
    for (int r = 0; r < 8; ++r) Xf[r * 260 + j] = acc[r];  // spill a
    __syncthreads();  // bar5: a visible

    // chains: vb = sum v*bmod; va = sum v*a; as = sum a  (each ascending)
    {
      const int w = j >> 6, l = j & 63;
      if (l < 6) {
        const int r = w + (l / 3) * 4;
        const int c = l % 3;
        const float* Yb = (c == 0) ? &bmlds[r][0] : &Xf[r * 260];
        const float* Xb = &vlds[r][0];
        float s = 0.0f;
        for (int k = 0; k < 256; ++k) {
          float x = Xb[k], y = Yb[k];
          float term = (c == 2) ? y : x * y;  // as-chain adds raw a (exact)
          s = s + term;
        }
        chainres[r][c] = s;
      }
    }
    __syncthreads();  // bar6

    if (j < 8) {
      const int r = j;
      float vb = chainres[r][0], va = chainres[r][1], as = chainres[r][2];
      float dE = ((-bsum_s[r] - as) + 2.0f * vb) + 2.0f * va;
      float z = dE / T;
      float p = xla_sigmoid(z);
      float u = tf_uniform(ksa, ksb, (unsigned)(brow + r));
      s0i[r] = (u < p) ? 1 : 0;
    }
    __syncthreads();  // bar7

    // v_next = s0 ? ve2 : 1-ve2  (== s0*ve2+(1-s0)*(1-ve2) bit-exact)
#pragma unroll
    for (int r = 0; r < 8; ++r) {
      vlds[r][j] = s0i[r] ? ve2[r] : 1.0f - ve2[r];
    }
    __syncthreads();  // bar8
  }

#pragma unroll
  for (int r = 0; r < 8; ++r)
    out[(brow + r) * 256 + j] = vlds[r][j];
  if (blockIdx.x == 0 && j < 32) out[2097152 + j] = temps[j];
}

}  // namespace

extern "C" void kernel_launch(void* const* d_in, const int* in_sizes, int n_in,
                              void* d_out, int out_size, void* d_ws, size_t ws_size,
                              hipStream_t stream) {
  (void)in_sizes; (void)n_in; (void)out_size;
  const float* cond = (const float*)d_in[0];
  const float* W    = (const float*)d_in[1];
  const float* bvec = (const float*)d_in[2];
  const float* cvec = (const float*)d_in[3];
  const float* fc1w = (const float*)d_in[4];
  const float* fc1b = (const float*)d_in[5];
  const float* fc2w = (const float*)d_in[6];
  const float* fc2b = (const float*)d_in[7];

  if (ws_size < WS_FLOATS * sizeof(float)) return;

  float* ws     = (float*)d_ws;
  float* temps  = ws + OFF_TEMPS;
  unsigned* keys = (unsigned*)(ws + OFF_KEYS);
  float* Wt     = ws + OFF_WT;
  float* fc2wT  = ws + OFF_F2T;
  float* x1     = ws + OFF_X1;
  float* bmod   = ws + OFF_BMOD;
  float* cmod   = ws + OFF_CMOD;
  float* out    = (float*)d_out;

  hipLaunchKernelGGL(kInitMeta, dim3(1), dim3(64), 0, stream, temps, keys);
  hipLaunchKernelGGL(kWt, dim3(256), dim3(256), 0, stream, W, Wt);
  hipLaunchKernelGGL(kTf2, dim3(256), dim3(256), 0, stream, fc2w, fc2wT);
  hipLaunchKernelGGL(kX1, dim3(2048), dim3(256), 0, stream, cond, fc1w, fc1b, x1);
  hipLaunchKernelGGL(kMod2, dim3(16384), dim3(256), 0, stream, x1, fc2wT, fc2b, bvec, cvec, bmod, cmod);
  hipLaunchKernelGGL(kGibbs, dim3(1024), dim3(256), 0, stream, W, Wt, bmod, cmod, keys, temps, out);
}

// Round 4
// 1929.510 us; speedup vs baseline: 3.0359x; 1.2823x over previous
//
#include <hip/hip_runtime.h>
#include <math.h>

#pragma clang fp contract(off)

namespace {

constexpr int kSteps = 32;

// ---- workspace layout (float slots) ----
constexpr size_t OFF_TEMPS = 0;        // 32 floats
constexpr size_t OFF_KEYS  = 64;       // 194 u32
constexpr size_t OFF_WP    = 512;      // 65536 (float4-packed W)
constexpr size_t OFF_WTP   = 66048;    // 65536 (float4-packed W^T)
constexpr size_t OFF_F2T   = 131584;   // 65536
constexpr size_t OFF_X1    = 197120;   // 524288
constexpr size_t OFF_BMOD  = 721408;   // 2097152
constexpr size_t OFF_CMOD  = 2818560;  // 2097152
constexpr size_t WS_FLOATS = 4915712;  // ~19.7 MB

// ================= threefry2x32 (JAX semantics) =================
__device__ __forceinline__ unsigned rotl32(unsigned v, int n) {
  return (v << n) | (v >> (32 - n));
}

__device__ __forceinline__ void tf_block(unsigned k0, unsigned k1,
                                         unsigned c0, unsigned c1,
                                         unsigned* o0, unsigned* o1) {
  unsigned k2 = k0 ^ k1 ^ 0x1BD11BDAu;
  unsigned x0 = c0 + k0;
  unsigned x1 = c1 + k1;
  x0 += x1; x1 = rotl32(x1, 13); x1 ^= x0;
  x0 += x1; x1 = rotl32(x1, 15); x1 ^= x0;
  x0 += x1; x1 = rotl32(x1, 26); x1 ^= x0;
  x0 += x1; x1 = rotl32(x1, 6);  x1 ^= x0;
  x0 += k1; x1 += k2 + 1u;
  x0 += x1; x1 = rotl32(x1, 17); x1 ^= x0;
  x0 += x1; x1 = rotl32(x1, 29); x1 ^= x0;
  x0 += x1; x1 = rotl32(x1, 16); x1 ^= x0;
  x0 += x1; x1 = rotl32(x1, 24); x1 ^= x0;
  x0 += k2; x1 += k0 + 2u;
  x0 += x1; x1 = rotl32(x1, 13); x1 ^= x0;
  x0 += x1; x1 = rotl32(x1, 15); x1 ^= x0;
  x0 += x1; x1 = rotl32(x1, 26); x1 ^= x0;
  x0 += x1; x1 = rotl32(x1, 6);  x1 ^= x0;
  x0 += k0; x1 += k1 + 3u;
  x0 += x1; x1 = rotl32(x1, 17); x1 ^= x0;
  x0 += x1; x1 = rotl32(x1, 29); x1 ^= x0;
  x0 += x1; x1 = rotl32(x1, 16); x1 ^= x0;
  x0 += x1; x1 = rotl32(x1, 24); x1 ^= x0;
  x0 += k1; x1 += k2 + 4u;
  x0 += x1; x1 = rotl32(x1, 13); x1 ^= x0;
  x0 += x1; x1 = rotl32(x1, 15); x1 ^= x0;
  x0 += x1; x1 = rotl32(x1, 26); x1 ^= x0;
  x0 += x1; x1 = rotl32(x1, 6);  x1 ^= x0;
  x0 += k2; x1 += k0 + 5u;
  *o0 = x0; *o1 = x1;
}

__device__ __forceinline__ float tf_uniform(unsigned k0, unsigned k1, unsigned idx) {
  unsigned o0, o1;
  tf_block(k0, k1, 0u, idx, &o0, &o1);
  unsigned bits = o0 ^ o1;
  float f = __uint_as_float((bits >> 9) | 0x3f800000u);
  return f - 1.0f;
}

// XLA EmitFastTanh (f32), plain mul/add.
__device__ __forceinline__ float xla_tanhf(float x) {
  if (fabsf(x) < 0.0004f) return x;
  float xc = fminf(fmaxf(x, -9.0f), 9.0f);
  float x2 = xc * xc;
  float num = -2.76076847742355e-16f;
  num = num * x2 + 2.00018790482477e-13f;
  num = num * x2 + -8.60467152213735e-11f;
  num = num * x2 + 5.12229709037114e-08f;
  num = num * x2 + 1.48572235717979e-05f;
  num = num * x2 + 6.37261928875436e-04f;
  num = num * x2 + 4.89352455891786e-03f;
  num = xc * num;
  float den = 1.19825839466702e-06f;
  den = den * x2 + 1.18534705686654e-04f;
  den = den * x2 + 2.26843463243900e-03f;
  den = den * x2 + 4.89352518554385e-03f;
  return num / den;
}

// XLA elemental kLogistic: 0.5 + 0.5 * tanh(0.5 * x)
__device__ __forceinline__ float xla_sigmoid(float x) {
  return 0.5f + 0.5f * xla_tanhf(0.5f * x);
}

// ================= setup kernels =================
__global__ __launch_bounds__(64) void kInitMeta(float* temps, unsigned* keys) {
  int t = threadIdx.x;
  if (t < 32) {
    float tf = (float)t;
    float arg = 0.1f * (tf - 16.0f);
    float e = (float)exp((double)arg);  // constant-folded by XLA w/ host expf
    float s = 1.0f / (1.0f + e);
    temps[t] = 1.0f + 4.0f * s;
  }
  if (t == 0) {
    unsigned cur0 = 0u, cur1 = 42u;  // jax.random.key(42)
    unsigned a0, a1, b0, b1;
    tf_block(cur0, cur1, 0u, 0u, &a0, &a1);  // carried key
    tf_block(cur0, cur1, 0u, 1u, &b0, &b1);  // init-v key
    keys[0] = b0; keys[1] = b1;
    cur0 = a0; cur1 = a1;
    for (int st = 0; st < kSteps; ++st) {
      unsigned n0, n1, kh0, kh1, ks0a, ks0b, kv0, kv1;
      tf_block(cur0, cur1, 0u, 0u, &n0, &n1);
      tf_block(cur0, cur1, 0u, 1u, &kh0, &kh1);
      tf_block(cur0, cur1, 0u, 2u, &ks0a, &ks0b);
      tf_block(cur0, cur1, 0u, 3u, &kv0, &kv1);
      keys[2 + st * 6 + 0] = kh0;  keys[2 + st * 6 + 1] = kh1;
      keys[2 + st * 6 + 2] = ks0a; keys[2 + st * 6 + 3] = ks0b;
      keys[2 + st * 6 + 4] = kv0;  keys[2 + st * 6 + 5] = kv1;
      cur0 = n0; cur1 = n1;
    }
  }
}

// Wp[kb][j] = float4{ W[4kb+0][j], W[4kb+1][j], W[4kb+2][j], W[4kb+3][j] }
__global__ __launch_bounds__(256) void kWp(const float* __restrict__ W, float4* __restrict__ Wp) {
  int idx = blockIdx.x * 256 + threadIdx.x;  // 65536
  int kb = idx >> 8, j = idx & 255;
  float4 w;
  w.x = W[(4 * kb + 0) * 256 + j];
  w.y = W[(4 * kb + 1) * 256 + j];
  w.z = W[(4 * kb + 2) * 256 + j];
  w.w = W[(4 * kb + 3) * 256 + j];
  Wp[idx] = w;
}

// Wtp[kb][i] = float4{ W[i][4kb+0], W[i][4kb+1], W[i][4kb+2], W[i][4kb+3] }
__global__ __launch_bounds__(256) void kWtp(const float* __restrict__ W, float4* __restrict__ Wtp) {
  int idx = blockIdx.x * 256 + threadIdx.x;  // 65536
  int kb = idx >> 8, i = idx & 255;
  float4 w;
  w.x = W[i * 256 + 4 * kb + 0];
  w.y = W[i * 256 + 4 * kb + 1];
  w.z = W[i * 256 + 4 * kb + 2];
  w.w = W[i * 256 + 4 * kb + 3];
  Wtp[idx] = w;
}

__global__ __launch_bounds__(256) void kTf2(const float* __restrict__ fc2w, float* __restrict__ fc2wT) {
  int idx = blockIdx.x * 256 + threadIdx.x;  // 65536
  int k = idx >> 10, o = idx & 1023;
  fc2wT[idx] = fc2w[o * 64 + k];             // fc2wT[k][o]
}

__global__ __launch_bounds__(256) void kX1(const float* __restrict__ cond,
                                           const float* __restrict__ fc1w,
                                           const float* __restrict__ fc1b,
                                           float* __restrict__ x1) {
  int idx = blockIdx.x * 256 + threadIdx.x;  // 524288
  int b = idx >> 6, hh = idx & 63;
  float acc = 0.0f;
  for (int k = 0; k < 16; ++k)
    acc = acc + cond[b * 16 + k] * fc1w[hh * 16 + k];
  acc = acc + fc1b[hh];
  x1[idx] = xla_tanhf(acc);
}

// coalesced via fc2wT; same op order as the passing kMod
__global__ __launch_bounds__(256) void kMod2(const float* __restrict__ x1,
                                             const float* __restrict__ fc2wT,
                                             const float* __restrict__ fc2b,
                                             const float* __restrict__ bvec,
                                             const float* __restrict__ cvec,
                                             float* __restrict__ bmod,
                                             float* __restrict__ cmod) {
  const int bid = blockIdx.x;        // 16384
  const int b = bid >> 1;
  const int half = bid & 1;
  const int ii = threadIdx.x;
  const int og = half * 512 + ii;
  const int ob = og + 256;
  float dg = 0.0f, db = 0.0f;
  for (int k = 0; k < 64; ++k) {
    float xv = x1[b * 64 + k];
    dg = dg + xv * fc2wT[k * 1024 + og];
    db = db + xv * fc2wT[k * 1024 + ob];
  }
  dg = dg + fc2b[og];
  db = db + fc2b[ob];
  float base = half ? cvec[ii] : bvec[ii];
  float outv = (1.0f + dg) * base + db;
  if (half) cmod[b * 256 + ii] = outv;
  else      bmod[b * 256 + ii] = outv;
}

// ================= fused 32-step Gibbs kernel =================
// Binary multiplicands (v,h in {0,1}) make products exact, so v_fma_f32 is
// bit-identical to the reference's separate mul+add. 1 VALU instr per MAC.
__global__ __launch_bounds__(256, 4) void kGibbs(
    const float4* __restrict__ Wp, const float4* __restrict__ Wtp,
    const float* __restrict__ bmod, const float* __restrict__ cmod,
    const unsigned* __restrict__ keys, const float* __restrict__ temps,
    float* __restrict__ out) {
  __shared__ float4 X4[8][65];       // row stride 260 floats, 16B-aligned
  __shared__ float  vlds[8][257];
  __shared__ float  bmlds[8][257];
  __shared__ float  cmlds[8][257];
  __shared__ float  chainres[8][3];
  __shared__ float  bsum_s[8];
  __shared__ int    s0i[8];

  float* Xf = reinterpret_cast<float*>(X4);

  const int j = threadIdx.x;
  const int brow = blockIdx.x * 8;

#pragma unroll
  for (int r = 0; r < 8; ++r) {
    bmlds[r][j] = bmod[(brow + r) * 256 + j];
    cmlds[r][j] = cmod[(brow + r) * 256 + j];
  }
  if (j < 8) s0i[j] = 1;
  {
    const unsigned k00 = keys[0], k01 = keys[1];
#pragma unroll
    for (int r = 0; r < 8; ++r) {
      float u = tf_uniform(k00, k01, (unsigned)((brow + r) * 256 + j));
      vlds[r][j] = (u < 0.5f) ? 1.0f : 0.0f;
    }
  }
  __syncthreads();
  if (j < 8) {  // bsum per row, sequential ascending (needed at step-0 bar6)
    float s = 0.0f;
    for (int k = 0; k < 256; ++k) s = s + bmlds[j][k];
    bsum_s[j] = s;
  }

  for (int t = 0; t < kSteps; ++t) {
    const float T = temps[t];
    const unsigned kh0 = keys[2 + t * 6 + 0], kh1 = keys[2 + t * 6 + 1];
    const unsigned ksa = keys[2 + t * 6 + 2], ksb = keys[2 + t * 6 + 3];
    const unsigned kv0 = keys[2 + t * 6 + 4], kv1 = keys[2 + t * 6 + 5];

    // (1) v_eff -> X  (s0 binary: select == s0*v+(1-s0)*(1-v) bit-exact)
#pragma unroll
    for (int r = 0; r < 8; ++r) {
      float vv = vlds[r][j];
      Xf[r * 260 + j] = s0i[r] ? vv : 1.0f - vv;
    }
    __syncthreads();  // bar1

    // (2) H MAC: acc[r] = sum_k veff[r][k]*W[k][j], ascending k.
    // fma exact: veff in {0,1} => product exact => single rounding == mul+add.
    float acc[8];
#pragma unroll
    for (int r = 0; r < 8; ++r) acc[r] = 0.0f;
    {
      const float4* wp = Wp + j;
      for (int kb = 0; kb < 64; ++kb) {
        float4 w4 = wp[kb << 8];
#pragma unroll
        for (int r = 0; r < 8; ++r) {
          float4 v4 = X4[r][kb];
          acc[r] = __builtin_fmaf(v4.x, w4.x, acc[r]);
          acc[r] = __builtin_fmaf(v4.y, w4.y, acc[r]);
          acc[r] = __builtin_fmaf(v4.z, w4.z, acc[r]);
          acc[r] = __builtin_fmaf(v4.w, w4.w, acc[r]);
        }
      }
    }

    // h draw
    float hv[8];
#pragma unroll
    for (int r = 0; r < 8; ++r) {
      float z = (acc[r] + cmlds[r][j]) / T;
      float p = xla_sigmoid(z);
      float u = tf_uniform(kh0, kh1, (unsigned)((brow + r) * 256 + j));
      hv[r] = (u < p) ? 1.0f : 0.0f;
    }
    __syncthreads();  // bar2: all H-MAC reads of X complete
#pragma unroll
    for (int r = 0; r < 8; ++r) Xf[r * 260 + j] = hv[r];
    __syncthreads();  // bar3: h visible

    // (4) AV MAC: acc[r] = sum_jj h[r][jj]*W[i=j][jj], ascending jj (fma exact)
#pragma unroll
    for (int r = 0; r < 8; ++r) acc[r] = 0.0f;
    {
      const float4* wp = Wtp + j;
      for (int kb = 0; kb < 64; ++kb) {
        float4 w4 = wp[kb << 8];
#pragma unroll
        for (int r = 0; r < 8; ++r) {
          float4 v4 = X4[r][kb];
          acc[r] = __builtin_fmaf(v4.x, w4.x, acc[r]);
          acc[r] = __builtin_fmaf(v4.y, w4.y, acc[r]);
          acc[r] = __builtin_fmaf(v4.z, w4.z, acc[r]);
          acc[r] = __builtin_fmaf(v4.w, w4.w, acc[r]);
        }
      }
    }

    // v candidate draws (independent of s0)
    float ve2[8];
#pragma unroll
    for (int r = 0; r < 8; ++r) {
      float z = (acc[r] + bmlds[r][j]) / T;
      float p = xla_sigmoid(z);
      float u = tf_uniform(kv0, kv1, (unsigned)((brow + r) * 256 + j));
      ve2[r] = (u < p) ? 1.0f : 0.0f;
    }

    __syncthreads();  // bar4: AV reads of X complete
#pragma unroll
    for (int r = 0; r < 8; ++r) Xf[r * 260 + j] = acc[r];  // spill a
    __syncthreads();  // bar5: a visible

    // chains on wave 0 only, lanes 0..23: r=l/3, c=l%3 (ascending, exact)
    // c==0: vb += v*bm (fma, v binary); c==1: va += v*a; c==2: as += a
    // (fma(1.0, y, s) == round(s+y) exactly)
    if (j < 64) {
      if (j < 24) {
        const int r = j / 3, c = j % 3;
        const float* A = &vlds[r][0];
        const float* Y = (c == 0) ? &bmlds[r][0] : &Xf[r * 260];
        float s = 0.0f;
        for (int k = 0; k < 256; ++k) {
          float xm = (c == 2) ? 1.0f : A[k];
          s = __builtin_fmaf(xm, Y[k], s);
        }
        chainres[r][c] = s;
      }
    }
    __syncthreads();  // bar6

    if (j < 8) {
      const int r = j;
      float vb = chainres[r][0], va = chainres[r][1], as = chainres[r][2];
      float dE = ((-bsum_s[r] - as) + 2.0f * vb) + 2.0f * va;
      float z = dE / T;
      float p = xla_sigmoid(z);
      float u = tf_uniform(ksa, ksb, (unsigned)(brow + r));
      s0i[r] = (u < p) ? 1 : 0;
    }
    __syncthreads();  // bar7

    // v_next = s0 ? ve2 : 1-ve2 (bit-exact select form)
#pragma unroll
    for (int r = 0; r < 8; ++r) {
      vlds[r][j] = s0i[r] ? ve2[r] : 1.0f - ve2[r];
    }
    __syncthreads();  // bar8
  }

#pragma unroll
  for (int r = 0; r < 8; ++r)
    out[(brow + r) * 256 + j] = vlds[r][j];
  if (blockIdx.x == 0 && j < 32) out[2097152 + j] = temps[j];
}

}  // namespace

extern "C" void kernel_launch(void* const* d_in, const int* in_sizes, int n_in,
                              void* d_out, int out_size, void* d_ws, size_t ws_size,
                              hipStream_t stream) {
  (void)in_sizes; (void)n_in; (void)out_size;
  const float* cond = (const float*)d_in[0];
  const float* W    = (const float*)d_in[1];
  const float* bvec = (const float*)d_in[2];
  const float* cvec = (const float*)d_in[3];
  const float* fc1w = (const float*)d_in[4];
  const float* fc1b = (const float*)d_in[5];
  const float* fc2w = (const float*)d_in[6];
  const float* fc2b = (const float*)d_in[7];

  if (ws_size < WS_FLOATS * sizeof(float)) return;

  float* ws      = (float*)d_ws;
  float* temps   = ws + OFF_TEMPS;
  unsigned* keys = (unsigned*)(ws + OFF_KEYS);
  float4* Wp     = (float4*)(ws + OFF_WP);
  float4* Wtp    = (float4*)(ws + OFF_WTP);
  float* fc2wT   = ws + OFF_F2T;
  float* x1      = ws + OFF_X1;
  float* bmod    = ws + OFF_BMOD;
  float* cmod    = ws + OFF_CMOD;
  float* out     = (float*)d_out;

  hipLaunchKernelGGL(kInitMeta, dim3(1), dim3(64), 0, stream, temps, keys);
  hipLaunchKernelGGL(kWp, dim3(256), dim3(256), 0, stream, W, Wp);
  hipLaunchKernelGGL(kWtp, dim3(256), dim3(256), 0, stream, W, Wtp);
  hipLaunchKernelGGL(kTf2, dim3(256), dim3(256), 0, stream, fc2w, fc2wT);
  hipLaunchKernelGGL(kX1, dim3(2048), dim3(256), 0, stream, cond, fc1w, fc1b, x1);
  hipLaunchKernelGGL(kMod2, dim3(16384), dim3(256), 0, stream, x1, fc2wT, fc2b, bvec, cvec, bmod, cmod);
  hipLaunchKernelGGL(kGibbs, dim3(1024), dim3(256), 0, stream, Wp, Wtp, bmod, cmod, keys, temps, out);
}